// Round 1
// baseline (194.232 us; speedup 1.0000x reference)
//
#include <hip/hip_runtime.h>
#include <hip/hip_bf16.h>
#include <cstdint>
#include <cstddef>

#define B_DIM 256
#define T_DIM 256
#define EMB   384
#define HEAD  64
#define QS    (B_DIM * T_DIM * HEAD)   // 4,194,304 elements per q/k/v array

typedef __attribute__((ext_vector_type(8))) short bf16x8;
typedef __attribute__((ext_vector_type(4))) float f32x4;
typedef __attribute__((ext_vector_type(4))) unsigned int u32x4;

__device__ __forceinline__ unsigned short f2bf(float f) {
    union { float f; unsigned int u; } v; v.f = f;
    unsigned int r = v.u + 0x7fffu + ((v.u >> 16) & 1u);  // round-nearest-even
    return (unsigned short)(r >> 16);
}

// ---------------------------------------------------------------------------
// Kernel 0: W prep — Wq|Wk|Wv (fp32 [384][64]) -> Wb bf16 [n=192][k=384]
// (transposed so the GEMM's B-fragment reads are contiguous ds_read_b128)
// ---------------------------------------------------------------------------
__global__ void wprep_kernel(const float* __restrict__ Wq, const float* __restrict__ Wk,
                             const float* __restrict__ Wv, unsigned short* __restrict__ Wb) {
    int idx = blockIdx.x * blockDim.x + threadIdx.x;
    if (idx >= 192 * EMB) return;
    int n = idx / EMB, k = idx - n * EMB;
    const float* W = (n < 64) ? Wq : (n < 128) ? Wk : Wv;
    Wb[idx] = f2bf(W[k * HEAD + (n & 63)]);
}

// ---------------------------------------------------------------------------
// Kernel 1: QKV projection. x [65536][384] fp32 @ Wb^T -> q,k,v bf16 [65536][64]
// Block = 64 M-rows x 192 N-cols, 4 waves; wave w owns 48 N-cols, all 64 rows.
// ---------------------------------------------------------------------------
__global__ __launch_bounds__(256) void qkv_kernel(const float* __restrict__ x,
                                                  const unsigned short* __restrict__ Wb,
                                                  unsigned short* __restrict__ qkv) {
    __shared__ unsigned short Xs[64][72];    // +8 pad keeps b128 reads conflict-free
    __shared__ unsigned short Ws[192][72];
    const int tid = threadIdx.x;
    const int w = tid >> 6, lane = tid & 63, qd = lane >> 4, l15 = lane & 15;
    const int m0 = blockIdx.x * 64;

    f32x4 acc[4][3];
#pragma unroll
    for (int mt = 0; mt < 4; ++mt)
#pragma unroll
        for (int nt = 0; nt < 3; ++nt) acc[mt][nt] = (f32x4){0.f, 0.f, 0.f, 0.f};

    for (int kk = 0; kk < EMB; kk += 64) {
        // stage X tile (64 rows x 64 k) fp32 -> bf16
#pragma unroll
        for (int s = 0; s < 4; ++s) {
            int i = tid + 256 * s;
            int row = i >> 4, c4 = (i & 15) << 2;
            const float4 vx = *(const float4*)(x + (size_t)(m0 + row) * EMB + kk + c4);
            unsigned int lo = (unsigned)f2bf(vx.x) | ((unsigned)f2bf(vx.y) << 16);
            unsigned int hi = (unsigned)f2bf(vx.z) | ((unsigned)f2bf(vx.w) << 16);
            *(uint2*)&Xs[row][c4] = make_uint2(lo, hi);
        }
        // stage W tile (192 n x 64 k) bf16 copy (L2-resident)
#pragma unroll
        for (int s = 0; s < 6; ++s) {
            int i = tid + 256 * s;
            int row = i >> 3, ch = (i & 7) << 3;
            *(u32x4*)&Ws[row][ch] = *(const u32x4*)(Wb + row * EMB + kk + ch);
        }
        __syncthreads();
#pragma unroll
        for (int kb = 0; kb < 2; ++kb) {
            bf16x8 a[4], bb[3];
#pragma unroll
            for (int mt = 0; mt < 4; ++mt)
                a[mt] = *(const bf16x8*)&Xs[16 * mt + l15][32 * kb + 8 * qd];
#pragma unroll
            for (int nt = 0; nt < 3; ++nt)
                bb[nt] = *(const bf16x8*)&Ws[48 * w + 16 * nt + l15][32 * kb + 8 * qd];
#pragma unroll
            for (int mt = 0; mt < 4; ++mt)
#pragma unroll
                for (int nt = 0; nt < 3; ++nt)
                    acc[mt][nt] = __builtin_amdgcn_mfma_f32_16x16x32_bf16(a[mt], bb[nt], acc[mt][nt], 0, 0, 0);
        }
        __syncthreads();
    }
    // epilogue: C/D layout col=l15, row=4*qd+reg; 16-col group never straddles q/k/v
#pragma unroll
    for (int nt = 0; nt < 3; ++nt) {
        int n = 48 * w + 16 * nt + l15;
        int arr = n >> 6, h = n & 63;
        unsigned short* dst = qkv + (size_t)arr * QS + h;
#pragma unroll
        for (int mt = 0; mt < 4; ++mt)
#pragma unroll
            for (int reg = 0; reg < 4; ++reg) {
                int row = m0 + 16 * mt + 4 * qd + reg;
                dst[(size_t)row * HEAD] = f2bf(acc[mt][nt][reg]);
            }
    }
}

// ---------------------------------------------------------------------------
// Kernel 2: fused causal attention, one block per batch.
// Wave w owns m-tiles {w, w+4, w+8, w+12} (rows 64*mt + 16*w + [0,16)) so the
// causal triangle is load-balanced across waves. No-max softmax (scores are
// tiny; exp2 cannot overflow; softmax shift-invariant).
// ---------------------------------------------------------------------------
__global__ __launch_bounds__(256, 1) void attn_kernel(const unsigned short* __restrict__ qkv,
                                                      float* __restrict__ out) {
    __shared__ unsigned short ks[256][72];     // K rows  (36,864 B)
    __shared__ unsigned short vT[64][264];     // V^T     (33,792 B)
    __shared__ unsigned short Ps[4][16][72];   // per-wave P strip (9,216 B)
    const int tid = threadIdx.x;
    const int w = tid >> 6, lane = tid & 63, qd = lane >> 4, l15 = lane & 15;
    const int b = blockIdx.x;
    const unsigned short* qb = qkv + (size_t)b * T_DIM * HEAD;
    const unsigned short* kb = qkv + (size_t)QS + (size_t)b * T_DIM * HEAD;
    const unsigned short* vb = qkv + 2 * (size_t)QS + (size_t)b * T_DIM * HEAD;

    // stage K (row-major) and V^T
#pragma unroll
    for (int s = 0; s < 8; ++s) {
        int i = tid + 256 * s;
        int row = i >> 3, ch = (i & 7) << 3;
        *(u32x4*)&ks[row][ch] = *(const u32x4*)(kb + row * HEAD + ch);
    }
#pragma unroll
    for (int s = 0; s < 4; ++s) {
        int i = tid + 256 * s;
        int t = i >> 2, d0 = (i & 3) << 4;
        union { u32x4 v; unsigned short u[8]; } t0, t1;
        t0.v = *(const u32x4*)(vb + t * HEAD + d0);
        t1.v = *(const u32x4*)(vb + t * HEAD + d0 + 8);
#pragma unroll
        for (int e = 0; e < 8; ++e) { vT[d0 + e][t] = t0.u[e]; vT[d0 + 8 + e][t] = t1.u[e]; }
    }
    // q fragments straight from global (A-layout: m=l15, k=8*qd+j)
    bf16x8 aq[4][2];
#pragma unroll
    for (int mt = 0; mt < 4; ++mt)
#pragma unroll
        for (int kbi = 0; kbi < 2; ++kbi)
            aq[mt][kbi] = *(const bf16x8*)(qb + (64 * mt + 16 * w + l15) * HEAD + 32 * kbi + 8 * qd);
    __syncthreads();

    f32x4 O[4][4];
    float l[4][4];
#pragma unroll
    for (int mt = 0; mt < 4; ++mt)
#pragma unroll
        for (int dn = 0; dn < 4; ++dn) O[mt][dn] = (f32x4){0.f, 0.f, 0.f, 0.f};
#pragma unroll
    for (int mt = 0; mt < 4; ++mt)
#pragma unroll
        for (int reg = 0; reg < 4; ++reg) l[mt][reg] = 0.f;

    const float cExp = 1.4426950408889634f / 19.595917942265423f; // log2(e)/sqrt(384)

    for (int mt = 0; mt < 4; ++mt) {
        for (int j = 0; j <= mt; ++j) {
            const int ntmax = (j == mt) ? w : 3;   // tiles beyond the diagonal are all-masked
            f32x4 S[4];
#pragma unroll
            for (int nt = 0; nt < 4; ++nt) {
                if (nt <= ntmax) {
                    bf16x8 b0 = *(const bf16x8*)&ks[64 * j + 16 * nt + l15][8 * qd];
                    bf16x8 b1 = *(const bf16x8*)&ks[64 * j + 16 * nt + l15][32 + 8 * qd];
                    f32x4 s = __builtin_amdgcn_mfma_f32_16x16x32_bf16(aq[mt][0], b0, (f32x4){0.f,0.f,0.f,0.f}, 0, 0, 0);
                    s = __builtin_amdgcn_mfma_f32_16x16x32_bf16(aq[mt][1], b1, s, 0, 0, 0);
                    S[nt] = s;
                }
            }
            // P = exp2(S*c) with causal mask; accumulate row sums; write strip
#pragma unroll
            for (int nt = 0; nt < 4; ++nt) {
#pragma unroll
                for (int reg = 0; reg < 4; ++reg) {
                    float p = 0.0f;
                    if (nt <= ntmax) {
                        p = exp2f(S[nt][reg] * cExp);
                        if (j == mt && nt == w && (l15 > 4 * qd + reg)) p = 0.0f;  // diagonal tile mask
                    }
                    l[mt][reg] += p;
                    Ps[w][4 * qd + reg][16 * nt + l15] = f2bf(p);
                }
            }
            // C-layout -> A-layout via per-wave LDS strip (wave-local, no barrier)
            bf16x8 ap0 = *(const bf16x8*)&Ps[w][l15][8 * qd];
            bf16x8 ap1 = *(const bf16x8*)&Ps[w][l15][32 + 8 * qd];
#pragma unroll
            for (int dn = 0; dn < 4; ++dn) {
                bf16x8 bv0 = *(const bf16x8*)&vT[16 * dn + l15][64 * j + 8 * qd];
                bf16x8 bv1 = *(const bf16x8*)&vT[16 * dn + l15][64 * j + 32 + 8 * qd];
                O[mt][dn] = __builtin_amdgcn_mfma_f32_16x16x32_bf16(ap0, bv0, O[mt][dn], 0, 0, 0);
                O[mt][dn] = __builtin_amdgcn_mfma_f32_16x16x32_bf16(ap1, bv1, O[mt][dn], 0, 0, 0);
            }
        }
    }

    // normalize and store: reduce row-sum across the 16 col-lanes (xor 1,2,4,8)
#pragma unroll
    for (int mt = 0; mt < 4; ++mt) {
#pragma unroll
        for (int reg = 0; reg < 4; ++reg) {
            float s = l[mt][reg];
            s += __shfl_xor(s, 1);
            s += __shfl_xor(s, 2);
            s += __shfl_xor(s, 4);
            s += __shfl_xor(s, 8);
            float inv = 1.0f / s;
            int row = 64 * mt + 16 * w + 4 * qd + reg;
            float* dst = out + ((size_t)b * T_DIM + row) * HEAD;
#pragma unroll
            for (int dn = 0; dn < 4; ++dn)
                dst[16 * dn + l15] = O[mt][dn][reg] * inv;
        }
    }
}

// ---------------------------------------------------------------------------
extern "C" void kernel_launch(void* const* d_in, const int* in_sizes, int n_in,
                              void* d_out, int out_size, void* d_ws, size_t ws_size,
                              hipStream_t stream) {
    const float* x  = (const float*)d_in[0];
    const float* Wq = (const float*)d_in[1];
    const float* Wk = (const float*)d_in[2];
    const float* Wv = (const float*)d_in[3];
    float* out = (float*)d_out;

    unsigned short* qkv = (unsigned short*)d_ws;          // 3 * QS bf16 = 25.2 MB
    unsigned short* Wb  = qkv + 3 * (size_t)QS;           // 192*384 bf16 = 147 KB

    wprep_kernel<<<(192 * EMB + 255) / 256, 256, 0, stream>>>(Wq, Wk, Wv, Wb);
    qkv_kernel<<<(B_DIM * T_DIM) / 64, 256, 0, stream>>>(x, Wb, qkv);
    attn_kernel<<<B_DIM, 256, 0, stream>>>(qkv, out);
}

// Round 2
// 184.053 us; speedup vs baseline: 1.0553x; 1.0553x over previous
//
#include <hip/hip_runtime.h>
#include <hip/hip_bf16.h>
#include <cstdint>
#include <cstddef>

#define B_DIM 256
#define T_DIM 256
#define EMB   384
#define HEAD  64
#define QS    (B_DIM * T_DIM * HEAD)   // elements per q/k/v array

typedef __attribute__((ext_vector_type(8))) short bf16x8;
typedef __attribute__((ext_vector_type(4))) float f32x4;
typedef __attribute__((ext_vector_type(4))) unsigned int u32x4;

__device__ __forceinline__ unsigned short f2bf(float f) {
    union { float f; unsigned int u; } v; v.f = f;
    unsigned int r = v.u + 0x7fffu + ((v.u >> 16) & 1u);  // RNE
    return (unsigned short)(r >> 16);
}

__device__ __forceinline__ unsigned int pkbf(float a, float b) {
#if __has_builtin(__builtin_amdgcn_cvt_pk_bf16_f32)
    typedef __attribute__((ext_vector_type(2))) __bf16 bf16x2_t;
    bf16x2_t r = __builtin_amdgcn_cvt_pk_bf16_f32(a, b);
    return *(unsigned int*)&r;
#else
    return (unsigned)f2bf(a) | ((unsigned)f2bf(b) << 16);
#endif
}

// ---------------------------------------------------------------------------
// Kernel 0: W prep — Wq|Wk|Wv fp32 [384][64] -> Wb bf16, chunk-permuted for
// global_load_lds staging. Chunk g = kkstep*1536 + r*8 + cs holds the 8
// k-values of source chunk c = cs ^ (r&7) of output-col r in k-step kkstep.
// This makes the unpadded LDS image conflict-free for swizzled b-frag reads.
// ---------------------------------------------------------------------------
__global__ void wprep_kernel(const float* __restrict__ Wq, const float* __restrict__ Wk,
                             const float* __restrict__ Wv, unsigned short* __restrict__ Wb) {
    int g = blockIdx.x * blockDim.x + threadIdx.x;
    if (g >= 9216) return;                 // 6 k-steps * 1536 chunks
    int kkstep = g / 1536, rem = g - kkstep * 1536;
    int r = rem >> 3, cs = rem & 7, c = cs ^ (r & 7);
    const float* W = (r < 64) ? Wq : (r < 128) ? Wk : Wv;
    int h = r & 63;
#pragma unroll
    for (int e = 0; e < 8; ++e) {
        int k = kkstep * 64 + c * 8 + e;
        Wb[(size_t)g * 8 + e] = f2bf(W[k * HEAD + h]);
    }
}

// ---------------------------------------------------------------------------
// Kernel 1: QKV projection. x [65536][384] fp32 @ Wb^T -> q,k,v bf16.
// 128x192 tile, 4 waves in 2x2 grid (wave = 64 rows x 96 cols, 4x6 accs).
// W staged with global_load_lds (16B), X staged reg->cvt->LDS.
// ---------------------------------------------------------------------------
__global__ __launch_bounds__(256) void qkv_kernel(const float* __restrict__ x,
                                                  const unsigned short* __restrict__ Wb,
                                                  unsigned short* __restrict__ qkv) {
    __shared__ unsigned short Xs[128][72];       // 18,432 B (+8 pad)
    __shared__ unsigned short Ws[192 * 64];      // 24,576 B, unpadded+swizzled
    const int tid = threadIdx.x;
    const int w = tid >> 6, lane = tid & 63, qd = lane >> 4, l15 = lane & 15;
    const int mh = w >> 1, nh = w & 1;
    const int m0 = blockIdx.x * 128;

    f32x4 acc[4][6];
#pragma unroll
    for (int mt = 0; mt < 4; ++mt)
#pragma unroll
        for (int nt = 0; nt < 6; ++nt) acc[mt][nt] = (f32x4){0.f, 0.f, 0.f, 0.f};

    for (int kk = 0; kk < 6; ++kk) {
        // W: 1536 16-B chunks via global_load_lds (wave-uniform LDS base)
#pragma unroll
        for (int s = 0; s < 6; ++s) {
            int idx = s * 256 + w * 64;  // wave-uniform part
            const unsigned short* gp = Wb + (size_t)(kk * 1536 + idx + lane) * 8;
            unsigned short* lp = Ws + (size_t)idx * 8;
            __builtin_amdgcn_global_load_lds(
                (const __attribute__((address_space(1))) unsigned int*)gp,
                (__attribute__((address_space(3))) unsigned int*)lp, 16, 0, 0);
        }
        // X: 128 rows x 64 k fp32 -> bf16
#pragma unroll
        for (int s = 0; s < 8; ++s) {
            int i = tid + 256 * s;
            int row = i >> 4, c4 = (i & 15) << 2;
            const float4 vx = *(const float4*)(x + (size_t)(m0 + row) * EMB + kk * 64 + c4);
            *(uint2*)&Xs[row][c4] = make_uint2(pkbf(vx.x, vx.y), pkbf(vx.z, vx.w));
        }
        __syncthreads();
#pragma unroll
        for (int kb = 0; kb < 2; ++kb) {
            bf16x8 a[4], bb[6];
#pragma unroll
            for (int mt = 0; mt < 4; ++mt)
                a[mt] = *(const bf16x8*)&Xs[64 * mh + 16 * mt + l15][32 * kb + 8 * qd];
#pragma unroll
            for (int nt = 0; nt < 6; ++nt) {
                int n = 96 * nh + 16 * nt + l15;
                bb[nt] = *(const bf16x8*)&Ws[n * 64 + (((4 * kb + qd) ^ (n & 7)) << 3)];
            }
#pragma unroll
            for (int mt = 0; mt < 4; ++mt)
#pragma unroll
                for (int nt = 0; nt < 6; ++nt)
                    acc[mt][nt] = __builtin_amdgcn_mfma_f32_16x16x32_bf16(a[mt], bb[nt], acc[mt][nt], 0, 0, 0);
        }
        __syncthreads();
    }
    // epilogue: C/D layout col=l15, row=4*qd+reg
#pragma unroll
    for (int nt = 0; nt < 6; ++nt) {
        int n = 96 * nh + 16 * nt + l15;
        int arr = n >> 6, h = n & 63;
        unsigned short* dst = qkv + (size_t)arr * QS + h;
#pragma unroll
        for (int mt = 0; mt < 4; ++mt)
#pragma unroll
            for (int reg = 0; reg < 4; ++reg) {
                int row = m0 + 64 * mh + 16 * mt + 4 * qd + reg;
                dst[(size_t)row * HEAD] = f2bf(acc[mt][nt][reg]);
            }
    }
}

// ---------------------------------------------------------------------------
// Kernel 2: fused causal attention, one block per batch, 8 waves.
// Wave w owns row-tiles {w, 15-w}: causal cost (w+1)+(16-w)=17 col-tiles and
// exactly 5 PV 64-chunks for every wave — perfectly balanced.
// ---------------------------------------------------------------------------
__global__ __launch_bounds__(512, 1) void attn_kernel(const unsigned short* __restrict__ qkv,
                                                      float* __restrict__ out) {
    __shared__ unsigned short ks[256][72];     // 36,864 B
    __shared__ unsigned short vT[64][264];     // 33,792 B
    __shared__ unsigned short Ps[8][16][72];   // 18,432 B per-wave P strips
    const int tid = threadIdx.x;
    const int w = tid >> 6, lane = tid & 63, qd = lane >> 4, l15 = lane & 15;
    const int b = blockIdx.x;
    const unsigned short* qb = qkv + (size_t)b * T_DIM * HEAD;
    const unsigned short* kb = qkv + (size_t)QS + (size_t)b * T_DIM * HEAD;
    const unsigned short* vb = qkv + 2 * (size_t)QS + (size_t)b * T_DIM * HEAD;

#pragma unroll
    for (int s = 0; s < 4; ++s) {
        int i = tid + 512 * s;
        int row = i >> 3, ch = (i & 7) << 3;
        *(u32x4*)&ks[row][ch] = *(const u32x4*)(kb + row * HEAD + ch);
    }
#pragma unroll
    for (int s = 0; s < 2; ++s) {
        int i = tid + 512 * s;
        int t = i >> 2, d0 = (i & 3) << 4;
        union { u32x4 v; unsigned short u[8]; } t0, t1;
        t0.v = *(const u32x4*)(vb + t * HEAD + d0);
        t1.v = *(const u32x4*)(vb + t * HEAD + d0 + 8);
#pragma unroll
        for (int e = 0; e < 8; ++e) { vT[d0 + e][t] = t0.u[e]; vT[d0 + 8 + e][t] = t1.u[e]; }
    }
    const int tiles[2] = { w, 15 - w };
    bf16x8 aq[2][2];
#pragma unroll
    for (int ti = 0; ti < 2; ++ti)
#pragma unroll
        for (int kbi = 0; kbi < 2; ++kbi)
            aq[ti][kbi] = *(const bf16x8*)(qb + (16 * tiles[ti] + l15) * HEAD + 32 * kbi + 8 * qd);
    __syncthreads();

    f32x4 O[2][4];
    float l[2][4];
#pragma unroll
    for (int ti = 0; ti < 2; ++ti) {
#pragma unroll
        for (int dn = 0; dn < 4; ++dn) O[ti][dn] = (f32x4){0.f, 0.f, 0.f, 0.f};
#pragma unroll
        for (int reg = 0; reg < 4; ++reg) l[ti][reg] = 0.f;
    }

    const float cExp = 1.4426950408889634f / 19.595917942265423f; // log2(e)/sqrt(384)

#pragma unroll
    for (int ti = 0; ti < 2; ++ti) {
        const int t = tiles[ti];
        for (int jc = 0; jc <= (t >> 2); ++jc) {
            const int ntmax = min(3, t - 4 * jc);
            f32x4 S[4];
#pragma unroll
            for (int nt = 0; nt < 4; ++nt) {
                if (nt <= ntmax) {
                    bf16x8 b0 = *(const bf16x8*)&ks[64 * jc + 16 * nt + l15][8 * qd];
                    bf16x8 b1 = *(const bf16x8*)&ks[64 * jc + 16 * nt + l15][32 + 8 * qd];
                    f32x4 s = __builtin_amdgcn_mfma_f32_16x16x32_bf16(aq[ti][0], b0, (f32x4){0.f,0.f,0.f,0.f}, 0, 0, 0);
                    s = __builtin_amdgcn_mfma_f32_16x16x32_bf16(aq[ti][1], b1, s, 0, 0, 0);
                    S[nt] = s;
                }
            }
#pragma unroll
            for (int nt = 0; nt < 4; ++nt) {
#pragma unroll
                for (int reg = 0; reg < 4; ++reg) {
                    float p = 0.0f;
                    if (nt <= ntmax) {
                        p = exp2f(S[nt][reg] * cExp);
                        if (4 * jc + nt == t && (l15 > 4 * qd + reg)) p = 0.0f;  // diagonal mask
                    }
                    l[ti][reg] += p;
                    Ps[w][4 * qd + reg][16 * nt + l15] = f2bf(p);
                }
            }
            // C-layout -> A-layout via wave-private LDS strip (no barrier)
            bf16x8 ap0 = *(const bf16x8*)&Ps[w][l15][8 * qd];
            bf16x8 ap1 = *(const bf16x8*)&Ps[w][l15][32 + 8 * qd];
#pragma unroll
            for (int dn = 0; dn < 4; ++dn) {
                bf16x8 bv0 = *(const bf16x8*)&vT[16 * dn + l15][64 * jc + 8 * qd];
                bf16x8 bv1 = *(const bf16x8*)&vT[16 * dn + l15][64 * jc + 32 + 8 * qd];
                O[ti][dn] = __builtin_amdgcn_mfma_f32_16x16x32_bf16(ap0, bv0, O[ti][dn], 0, 0, 0);
                O[ti][dn] = __builtin_amdgcn_mfma_f32_16x16x32_bf16(ap1, bv1, O[ti][dn], 0, 0, 0);
            }
        }
    }

#pragma unroll
    for (int ti = 0; ti < 2; ++ti) {
#pragma unroll
        for (int reg = 0; reg < 4; ++reg) {
            float s = l[ti][reg];
            s += __shfl_xor(s, 1);
            s += __shfl_xor(s, 2);
            s += __shfl_xor(s, 4);
            s += __shfl_xor(s, 8);
            float inv = 1.0f / s;
            int row = 16 * tiles[ti] + 4 * qd + reg;
            float* dst = out + ((size_t)b * T_DIM + row) * HEAD;
#pragma unroll
            for (int dn = 0; dn < 4; ++dn)
                dst[16 * dn + l15] = O[ti][dn][reg] * inv;
        }
    }
}

// ---------------------------------------------------------------------------
extern "C" void kernel_launch(void* const* d_in, const int* in_sizes, int n_in,
                              void* d_out, int out_size, void* d_ws, size_t ws_size,
                              hipStream_t stream) {
    const float* x  = (const float*)d_in[0];
    const float* Wq = (const float*)d_in[1];
    const float* Wk = (const float*)d_in[2];
    const float* Wv = (const float*)d_in[3];
    float* out = (float*)d_out;

    unsigned short* qkv = (unsigned short*)d_ws;          // 3 * QS bf16 = 25.2 MB
    unsigned short* Wb  = qkv + 3 * (size_t)QS;           // 9216*8 bf16 = 147 KB

    wprep_kernel<<<36, 256, 0, stream>>>(Wq, Wk, Wv, Wb);
    qkv_kernel<<<(B_DIM * T_DIM) / 128, 256, 0, stream>>>(x, Wb, qkv);
    attn_kernel<<<B_DIM, 512, 0, stream>>>(qkv, out);
}

// Round 3
// 174.613 us; speedup vs baseline: 1.1124x; 1.0541x over previous
//
#include <hip/hip_runtime.h>
#include <hip/hip_bf16.h>
#include <cstdint>
#include <cstddef>

#define B_DIM 256
#define T_DIM 256
#define EMB   384
#define HEAD  64

typedef __attribute__((ext_vector_type(8))) short bf16x8;
typedef __attribute__((ext_vector_type(4))) float f32x4;
typedef __attribute__((ext_vector_type(4))) unsigned int u32x4;

__device__ __forceinline__ unsigned short f2bf(float f) {
    union { float f; unsigned int u; } v; v.f = f;
    unsigned int r = v.u + 0x7fffu + ((v.u >> 16) & 1u);  // RNE
    return (unsigned short)(r >> 16);
}

__device__ __forceinline__ unsigned int pkbf(float a, float b) {
#if __has_builtin(__builtin_amdgcn_cvt_pk_bf16_f32)
    typedef __attribute__((ext_vector_type(2))) __bf16 bf16x2_t;
    bf16x2_t r = __builtin_amdgcn_cvt_pk_bf16_f32(a, b);
    return *(unsigned int*)&r;
#else
    return (unsigned)f2bf(a) | ((unsigned)f2bf(b) << 16);
#endif
}

// ---------------------------------------------------------------------------
// Kernel 0: W prep — Wq|Wk|Wv fp32 [384][64] -> Wb bf16, chunk-permuted for
// global_load_lds staging. Chunk g = kkstep*1536 + r*8 + cs holds the 8
// k-values of source chunk c = cs ^ (r&7) of output-col r in k-step kkstep.
// Makes the unpadded LDS image conflict-free for swizzled B-frag reads.
// ---------------------------------------------------------------------------
__global__ void wprep_kernel(const float* __restrict__ Wq, const float* __restrict__ Wk,
                             const float* __restrict__ Wv, unsigned short* __restrict__ Wb) {
    int g = blockIdx.x * blockDim.x + threadIdx.x;
    if (g >= 9216) return;                 // 6 k-steps * 1536 chunks
    int kkstep = g / 1536, rem = g - kkstep * 1536;
    int r = rem >> 3, cs = rem & 7, c = cs ^ (r & 7);
    const float* W = (r < 64) ? Wq : (r < 128) ? Wk : Wv;
    int h = r & 63;
#pragma unroll
    for (int e = 0; e < 8; ++e) {
        int k = kkstep * 64 + c * 8 + e;
        Wb[(size_t)g * 8 + e] = f2bf(W[k * HEAD + h]);
    }
}

// ---------------------------------------------------------------------------
// Fused kernel: one block per batch, 512 threads (8 waves).
// Phase 1: QKV GEMM M=256(tok) x N=192(ch), K=384. Wave (mh,nh) = 64 rows x
//   96 cols, acc[4][6]. X reg-prefetch + W LDS-dbuf via global_load_lds,
//   prefetch issued AFTER barrier(2) so vmcnt drain lands after compute.
// Phase 2: acc scatters q/k/vT straight to LDS; attention runs fully in LDS.
//   Wave w owns row-tiles {w, 15-w}: 17 col-tiles / 5 PV chunks each wave.
// ---------------------------------------------------------------------------
__global__ __launch_bounds__(512, 2) void fused_kernel(const float* __restrict__ x,
                                                       const unsigned short* __restrict__ Wb,
                                                       float* __restrict__ out) {
    __shared__ union SM {
        struct { unsigned short Xs[256][72]; unsigned short Ws[2][12288]; } p1;   // 86,016 B
        struct { unsigned short qs[256][72]; unsigned short ks[256][72];
                 unsigned short vT[64][264]; unsigned short Ps[8][16][72]; } p2;  // 125,952 B
    } sm;

    const int tid = threadIdx.x;
    const int w = tid >> 6, lane = tid & 63, qd = lane >> 4, l15 = lane & 15;
    const int mh = w >> 1, nh = w & 1;
    const int b = blockIdx.x;
    const float* xb = x + (size_t)b * T_DIM * EMB;

    f32x4 acc[4][6];
#pragma unroll
    for (int mt = 0; mt < 4; ++mt)
#pragma unroll
        for (int nt = 0; nt < 6; ++nt) acc[mt][nt] = (f32x4){0.f, 0.f, 0.f, 0.f};

    float4 xr[8];
    // prologue: issue W(0) glds + x(0) register loads
#pragma unroll
    for (int s = 0; s < 3; ++s) {
        int idx = s * 512 + w * 64;  // wave-uniform
        const unsigned short* gp = Wb + (size_t)(idx + lane) * 8;
        unsigned short* lp = &sm.p1.Ws[0][idx * 8];
        __builtin_amdgcn_global_load_lds(
            (const __attribute__((address_space(1))) unsigned int*)gp,
            (__attribute__((address_space(3))) unsigned int*)lp, 16, 0, 0);
    }
#pragma unroll
    for (int s = 0; s < 8; ++s) {
        int i = tid + 512 * s;
        int row = i >> 4, c4 = (i & 15) << 2;
        xr[s] = *(const float4*)(xb + (size_t)row * EMB + c4);
    }

    for (int kk = 0; kk < 6; ++kk) {
        __syncthreads();                       // (1) prev compute done; drains xr & W(kk)
#pragma unroll
        for (int s = 0; s < 8; ++s) {
            int i = tid + 512 * s;
            int row = i >> 4, c4 = (i & 15) << 2;
            *(uint2*)&sm.p1.Xs[row][c4] = make_uint2(pkbf(xr[s].x, xr[s].y), pkbf(xr[s].z, xr[s].w));
        }
        __syncthreads();                       // (2) Xs visible
        if (kk < 5) {                          // prefetch AFTER barrier: drained after compute
#pragma unroll
            for (int s = 0; s < 3; ++s) {
                int idx = s * 512 + w * 64;
                const unsigned short* gp = Wb + (size_t)((kk + 1) * 1536 + idx + lane) * 8;
                unsigned short* lp = &sm.p1.Ws[(kk + 1) & 1][idx * 8];
                __builtin_amdgcn_global_load_lds(
                    (const __attribute__((address_space(1))) unsigned int*)gp,
                    (__attribute__((address_space(3))) unsigned int*)lp, 16, 0, 0);
            }
#pragma unroll
            for (int s = 0; s < 8; ++s) {
                int i = tid + 512 * s;
                int row = i >> 4, c4 = (i & 15) << 2;
                xr[s] = *(const float4*)(xb + (size_t)row * EMB + (kk + 1) * 64 + c4);
            }
        }
#pragma unroll
        for (int kb = 0; kb < 2; ++kb) {
            bf16x8 a[4], bb[6];
#pragma unroll
            for (int mt = 0; mt < 4; ++mt)
                a[mt] = *(const bf16x8*)&sm.p1.Xs[64 * mh + 16 * mt + l15][32 * kb + 8 * qd];
#pragma unroll
            for (int nt = 0; nt < 6; ++nt) {
                int n = 96 * nh + 16 * nt + l15;
                bb[nt] = *(const bf16x8*)&sm.p1.Ws[kk & 1][n * 64 + (((4 * kb + qd) ^ (n & 7)) << 3)];
            }
#pragma unroll
            for (int mt = 0; mt < 4; ++mt)
#pragma unroll
                for (int nt = 0; nt < 6; ++nt)
                    acc[mt][nt] = __builtin_amdgcn_mfma_f32_16x16x32_bf16(a[mt], bb[nt], acc[mt][nt], 0, 0, 0);
        }
    }
    __syncthreads();                           // (3) all GEMM LDS reads done

    // scatter acc -> qs / ks / vT  (C/D layout: col=l15(ch), row=4qd+reg(tok))
#pragma unroll
    for (int nt = 0; nt < 6; ++nt) {
        int n = 96 * nh + 16 * nt + l15;
        int arr = n >> 6, h = n & 63;          // wave-uniform arr per nt
#pragma unroll
        for (int mt = 0; mt < 4; ++mt)
#pragma unroll
            for (int reg = 0; reg < 4; ++reg) {
                int tok = 64 * mh + 16 * mt + 4 * qd + reg;
                unsigned short val = f2bf(acc[mt][nt][reg]);
                if (arr == 0)      sm.p2.qs[tok][h] = val;
                else if (arr == 1) sm.p2.ks[tok][h] = val;
                else               sm.p2.vT[h][tok] = val;
            }
    }
    __syncthreads();                           // (4) q/k/vT ready

    // ---------------- attention, fully in LDS ----------------
    const int tiles[2] = { w, 15 - w };
    bf16x8 aq[2][2];
#pragma unroll
    for (int ti = 0; ti < 2; ++ti)
#pragma unroll
        for (int kbi = 0; kbi < 2; ++kbi)
            aq[ti][kbi] = *(const bf16x8*)&sm.p2.qs[16 * tiles[ti] + l15][32 * kbi + 8 * qd];

    f32x4 O[2][4];
    float l[2][4];
#pragma unroll
    for (int ti = 0; ti < 2; ++ti) {
#pragma unroll
        for (int dn = 0; dn < 4; ++dn) O[ti][dn] = (f32x4){0.f, 0.f, 0.f, 0.f};
#pragma unroll
        for (int reg = 0; reg < 4; ++reg) l[ti][reg] = 0.f;
    }

    const float cExp = 1.4426950408889634f / 19.595917942265423f; // log2(e)/sqrt(384)

#pragma unroll
    for (int ti = 0; ti < 2; ++ti) {
        const int t = tiles[ti];
        for (int jc = 0; jc <= (t >> 2); ++jc) {
            const int ntmax = min(3, t - 4 * jc);
            f32x4 S[4];
#pragma unroll
            for (int nt = 0; nt < 4; ++nt) {
                if (nt <= ntmax) {
                    bf16x8 b0 = *(const bf16x8*)&sm.p2.ks[64 * jc + 16 * nt + l15][8 * qd];
                    bf16x8 b1 = *(const bf16x8*)&sm.p2.ks[64 * jc + 16 * nt + l15][32 + 8 * qd];
                    f32x4 s = __builtin_amdgcn_mfma_f32_16x16x32_bf16(aq[ti][0], b0, (f32x4){0.f,0.f,0.f,0.f}, 0, 0, 0);
                    s = __builtin_amdgcn_mfma_f32_16x16x32_bf16(aq[ti][1], b1, s, 0, 0, 0);
                    S[nt] = s;
                }
            }
#pragma unroll
            for (int nt = 0; nt < 4; ++nt) {
#pragma unroll
                for (int reg = 0; reg < 4; ++reg) {
                    float p = 0.0f;
                    if (nt <= ntmax) {
                        p = exp2f(S[nt][reg] * cExp);
                        if (4 * jc + nt == t && (l15 > 4 * qd + reg)) p = 0.0f;  // diagonal mask
                    }
                    l[ti][reg] += p;
                    sm.p2.Ps[w][4 * qd + reg][16 * nt + l15] = f2bf(p);
                }
            }
            // C-layout -> A-layout via wave-private strip (no barrier needed)
            bf16x8 ap0 = *(const bf16x8*)&sm.p2.Ps[w][l15][8 * qd];
            bf16x8 ap1 = *(const bf16x8*)&sm.p2.Ps[w][l15][32 + 8 * qd];
#pragma unroll
            for (int dn = 0; dn < 4; ++dn) {
                bf16x8 bv0 = *(const bf16x8*)&sm.p2.vT[16 * dn + l15][64 * jc + 8 * qd];
                bf16x8 bv1 = *(const bf16x8*)&sm.p2.vT[16 * dn + l15][64 * jc + 32 + 8 * qd];
                O[ti][dn] = __builtin_amdgcn_mfma_f32_16x16x32_bf16(ap0, bv0, O[ti][dn], 0, 0, 0);
                O[ti][dn] = __builtin_amdgcn_mfma_f32_16x16x32_bf16(ap1, bv1, O[ti][dn], 0, 0, 0);
            }
        }
    }

#pragma unroll
    for (int ti = 0; ti < 2; ++ti) {
#pragma unroll
        for (int reg = 0; reg < 4; ++reg) {
            float s = l[ti][reg];
            s += __shfl_xor(s, 1);
            s += __shfl_xor(s, 2);
            s += __shfl_xor(s, 4);
            s += __shfl_xor(s, 8);
            float inv = 1.0f / s;
            int row = 16 * tiles[ti] + 4 * qd + reg;
            float* dst = out + ((size_t)b * T_DIM + row) * HEAD;
#pragma unroll
            for (int dn = 0; dn < 4; ++dn)
                dst[16 * dn + l15] = O[ti][dn][reg] * inv;
        }
    }
}

// ---------------------------------------------------------------------------
extern "C" void kernel_launch(void* const* d_in, const int* in_sizes, int n_in,
                              void* d_out, int out_size, void* d_ws, size_t ws_size,
                              hipStream_t stream) {
    const float* x  = (const float*)d_in[0];
    const float* Wq = (const float*)d_in[1];
    const float* Wk = (const float*)d_in[2];
    const float* Wv = (const float*)d_in[3];
    float* out = (float*)d_out;

    unsigned short* Wb = (unsigned short*)d_ws;   // 9216*8 bf16 = 147 KB

    wprep_kernel<<<36, 256, 0, stream>>>(Wq, Wk, Wv, Wb);
    fused_kernel<<<B_DIM, 512, 0, stream>>>(x, Wb, out);
}

// Round 4
// 171.410 us; speedup vs baseline: 1.1331x; 1.0187x over previous
//
#include <hip/hip_runtime.h>
#include <hip/hip_bf16.h>
#include <cstdint>
#include <cstddef>

#define B_DIM 256
#define T_DIM 256
#define EMB   384
#define HEAD  64

typedef __attribute__((ext_vector_type(8))) short bf16x8;
typedef __attribute__((ext_vector_type(4))) float f32x4;
typedef __attribute__((ext_vector_type(4))) unsigned int u32x4;

__device__ __forceinline__ unsigned short f2bf(float f) {
    union { float f; unsigned int u; } v; v.f = f;
    unsigned int r = v.u + 0x7fffu + ((v.u >> 16) & 1u);  // RNE
    return (unsigned short)(r >> 16);
}

__device__ __forceinline__ unsigned int pkbf(float a, float b) {
#if __has_builtin(__builtin_amdgcn_cvt_pk_bf16_f32)
    typedef __attribute__((ext_vector_type(2))) __bf16 bf16x2_t;
    bf16x2_t r = __builtin_amdgcn_cvt_pk_bf16_f32(a, b);
    return *(unsigned int*)&r;
#else
    return (unsigned)f2bf(a) | ((unsigned)f2bf(b) << 16);
#endif
}

// ---------------------------------------------------------------------------
// Kernel 0: W prep — Wq|Wk|Wv fp32 [384][64] -> Wb bf16, chunk-permuted for
// global_load_lds staging. Chunk g = kkstep*1536 + r*8 + cs holds the 8
// k-values of source chunk c = cs ^ (r&7) of output-col r in k-step kkstep.
// Makes the unpadded LDS image conflict-free for swizzled B-frag reads.
// ---------------------------------------------------------------------------
__global__ void wprep_kernel(const float* __restrict__ Wq, const float* __restrict__ Wk,
                             const float* __restrict__ Wv, unsigned short* __restrict__ Wb) {
    int g = blockIdx.x * blockDim.x + threadIdx.x;
    if (g >= 9216) return;                 // 6 k-steps * 1536 chunks
    int kkstep = g / 1536, rem = g - kkstep * 1536;
    int r = rem >> 3, cs = rem & 7, c = cs ^ (r & 7);
    const float* W = (r < 64) ? Wq : (r < 128) ? Wk : Wv;
    int h = r & 63;
    unsigned short tmp[8];
#pragma unroll
    for (int e = 0; e < 8; ++e) {
        int k = kkstep * 64 + c * 8 + e;
        tmp[e] = f2bf(W[k * HEAD + h]);
    }
    *(u32x4*)(Wb + (size_t)g * 8) = *(u32x4*)tmp;
}

// ---------------------------------------------------------------------------
// Fused kernel: one block per batch, 512 threads (8 waves), 1 block/CU.
// Phase 1: QKV GEMM M=256(tok) x N=192(ch), K=384. Wave (mh,nh) = 64 rows x
//   96 cols, acc[4][6]. Xs AND Ws double-buffered -> ONE barrier per k-step;
//   W via global_load_lds(16B), x via reg prefetch, both issued right after
//   the barrier so the vmcnt drain lands after the MFMA block.
// Phase 2: acc scatters q/k/vT straight to LDS (vT packed b64); attention
//   runs fully in LDS. Wave w owns row-tiles {w, 15-w}: 17 col-tiles and 5
//   PV chunks per wave — perfectly balanced causal triangle.
// ---------------------------------------------------------------------------
__global__ __launch_bounds__(512, 2) void fused_kernel(const float* __restrict__ x,
                                                       const unsigned short* __restrict__ Wb,
                                                       float* __restrict__ out) {
    __shared__ union SM {
        struct { unsigned short Xs[2][256][72]; unsigned short Ws[2][12288]; } p1;  // 122,880 B
        struct { unsigned short qs[256][72]; unsigned short ks[256][72];
                 unsigned short vT[64][264]; unsigned short Ps[8][16][72]; } p2;    // 125,952 B
    } sm;

    const int tid = threadIdx.x;
    const int w = tid >> 6, lane = tid & 63, qd = lane >> 4, l15 = lane & 15;
    const int mh = w >> 1, nh = w & 1;
    const int b = blockIdx.x;
    const float* xb = x + (size_t)b * T_DIM * EMB;
    const int xrow = tid >> 4, xc4 = (tid & 15) << 2;   // per-thread x-stage coords

    f32x4 acc[4][6];
#pragma unroll
    for (int mt = 0; mt < 4; ++mt)
#pragma unroll
        for (int nt = 0; nt < 6; ++nt) acc[mt][nt] = (f32x4){0.f, 0.f, 0.f, 0.f};

    float4 xr[8];
    // prologue: W(0) glds + x(0) load + convert into buffers 0
#pragma unroll
    for (int s = 0; s < 3; ++s) {
        int idx = s * 512 + w * 64;  // wave-uniform base
        const unsigned short* gp = Wb + (size_t)(idx + lane) * 8;
        unsigned short* lp = &sm.p1.Ws[0][idx * 8];
        __builtin_amdgcn_global_load_lds(
            (const __attribute__((address_space(1))) unsigned int*)gp,
            (__attribute__((address_space(3))) unsigned int*)lp, 16, 0, 0);
    }
#pragma unroll
    for (int s = 0; s < 8; ++s)
        xr[s] = *(const float4*)(xb + (size_t)(xrow + 32 * s) * EMB + xc4);
#pragma unroll
    for (int s = 0; s < 8; ++s)
        *(uint2*)&sm.p1.Xs[0][xrow + 32 * s][xc4] = make_uint2(pkbf(xr[s].x, xr[s].y), pkbf(xr[s].z, xr[s].w));

    for (int kk = 0; kk < 6; ++kk) {
        __syncthreads();   // buffers[kk&1] ready (LDS writes + glds vmcnt drained)
        if (kk < 5) {      // prefetch into buffers[(kk+1)&1]; drained at next barrier
#pragma unroll
            for (int s = 0; s < 3; ++s) {
                int idx = s * 512 + w * 64;
                const unsigned short* gp = Wb + (size_t)((kk + 1) * 1536 + idx + lane) * 8;
                unsigned short* lp = &sm.p1.Ws[(kk + 1) & 1][idx * 8];
                __builtin_amdgcn_global_load_lds(
                    (const __attribute__((address_space(1))) unsigned int*)gp,
                    (__attribute__((address_space(3))) unsigned int*)lp, 16, 0, 0);
            }
#pragma unroll
            for (int s = 0; s < 8; ++s)
                xr[s] = *(const float4*)(xb + (size_t)(xrow + 32 * s) * EMB + (kk + 1) * 64 + xc4);
        }
#pragma unroll
        for (int kb = 0; kb < 2; ++kb) {
            bf16x8 a[4], bb[6];
#pragma unroll
            for (int mt = 0; mt < 4; ++mt)
                a[mt] = *(const bf16x8*)&sm.p1.Xs[kk & 1][64 * mh + 16 * mt + l15][32 * kb + 8 * qd];
#pragma unroll
            for (int nt = 0; nt < 6; ++nt) {
                int n = 96 * nh + 16 * nt + l15;
                bb[nt] = *(const bf16x8*)&sm.p1.Ws[kk & 1][n * 64 + (((4 * kb + qd) ^ (n & 7)) << 3)];
            }
#pragma unroll
            for (int mt = 0; mt < 4; ++mt)
#pragma unroll
                for (int nt = 0; nt < 6; ++nt)
                    acc[mt][nt] = __builtin_amdgcn_mfma_f32_16x16x32_bf16(a[mt], bb[nt], acc[mt][nt], 0, 0, 0);
        }
        if (kk < 5) {      // convert next X tile after compute (xr latency hidden)
#pragma unroll
            for (int s = 0; s < 8; ++s)
                *(uint2*)&sm.p1.Xs[(kk + 1) & 1][xrow + 32 * s][xc4] =
                    make_uint2(pkbf(xr[s].x, xr[s].y), pkbf(xr[s].z, xr[s].w));
        }
    }
    __syncthreads();       // all GEMM LDS reads done; safe to repurpose union

    // scatter acc -> qs / ks / vT  (C/D layout: col=l15(ch), row=4*qd+reg(tok))
#pragma unroll
    for (int nt = 0; nt < 6; ++nt) {
        int n = 96 * nh + 16 * nt + l15;
        int arr = n >> 6, h = n & 63;          // arr is wave-uniform per nt
        if (arr == 2) {                        // vT: token-contiguous -> packed b64
#pragma unroll
            for (int mt = 0; mt < 4; ++mt) {
                int tok0 = 64 * mh + 16 * mt + 4 * qd;
                *(uint2*)&sm.p2.vT[h][tok0] = make_uint2(
                    pkbf(acc[mt][nt][0], acc[mt][nt][1]),
                    pkbf(acc[mt][nt][2], acc[mt][nt][3]));
            }
        } else {
#pragma unroll
            for (int mt = 0; mt < 4; ++mt)
#pragma unroll
                for (int reg = 0; reg < 4; ++reg) {
                    int tok = 64 * mh + 16 * mt + 4 * qd + reg;
                    unsigned short val = f2bf(acc[mt][nt][reg]);
                    if (arr == 0) sm.p2.qs[tok][h] = val;
                    else          sm.p2.ks[tok][h] = val;
                }
        }
    }
    __syncthreads();       // q/k/vT ready

    // ---------------- attention, fully in LDS ----------------
    const int tiles[2] = { w, 15 - w };
    bf16x8 aq[2][2];
#pragma unroll
    for (int ti = 0; ti < 2; ++ti)
#pragma unroll
        for (int kbi = 0; kbi < 2; ++kbi)
            aq[ti][kbi] = *(const bf16x8*)&sm.p2.qs[16 * tiles[ti] + l15][32 * kbi + 8 * qd];

    f32x4 O[2][4];
    float l[2][4];
#pragma unroll
    for (int ti = 0; ti < 2; ++ti) {
#pragma unroll
        for (int dn = 0; dn < 4; ++dn) O[ti][dn] = (f32x4){0.f, 0.f, 0.f, 0.f};
#pragma unroll
        for (int reg = 0; reg < 4; ++reg) l[ti][reg] = 0.f;
    }

    const float cExp = 1.4426950408889634f / 19.595917942265423f; // log2(e)/sqrt(384)

#pragma unroll
    for (int ti = 0; ti < 2; ++ti) {
        const int t = tiles[ti];
        for (int jc = 0; jc <= (t >> 2); ++jc) {
            const int ntmax = min(3, t - 4 * jc);
            f32x4 S[4];
#pragma unroll
            for (int nt = 0; nt < 4; ++nt) {
                if (nt <= ntmax) {
                    bf16x8 b0 = *(const bf16x8*)&sm.p2.ks[64 * jc + 16 * nt + l15][8 * qd];
                    bf16x8 b1 = *(const bf16x8*)&sm.p2.ks[64 * jc + 16 * nt + l15][32 + 8 * qd];
                    f32x4 s = __builtin_amdgcn_mfma_f32_16x16x32_bf16(aq[ti][0], b0, (f32x4){0.f,0.f,0.f,0.f}, 0, 0, 0);
                    s = __builtin_amdgcn_mfma_f32_16x16x32_bf16(aq[ti][1], b1, s, 0, 0, 0);
                    S[nt] = s;
                }
            }
#pragma unroll
            for (int nt = 0; nt < 4; ++nt) {
#pragma unroll
                for (int reg = 0; reg < 4; ++reg) {
                    float p = 0.0f;
                    if (nt <= ntmax) {
                        p = exp2f(S[nt][reg] * cExp);
                        if (4 * jc + nt == t && (l15 > 4 * qd + reg)) p = 0.0f;  // diagonal mask
                    }
                    l[ti][reg] += p;
                    sm.p2.Ps[w][4 * qd + reg][16 * nt + l15] = f2bf(p);
                }
            }
            // C-layout -> A-layout via wave-private strip (no barrier needed)
            bf16x8 ap0 = *(const bf16x8*)&sm.p2.Ps[w][l15][8 * qd];
            bf16x8 ap1 = *(const bf16x8*)&sm.p2.Ps[w][l15][32 + 8 * qd];
#pragma unroll
            for (int dn = 0; dn < 4; ++dn) {
                bf16x8 bv0 = *(const bf16x8*)&sm.p2.vT[16 * dn + l15][64 * jc + 8 * qd];
                bf16x8 bv1 = *(const bf16x8*)&sm.p2.vT[16 * dn + l15][64 * jc + 32 + 8 * qd];
                O[ti][dn] = __builtin_amdgcn_mfma_f32_16x16x32_bf16(ap0, bv0, O[ti][dn], 0, 0, 0);
                O[ti][dn] = __builtin_amdgcn_mfma_f32_16x16x32_bf16(ap1, bv1, O[ti][dn], 0, 0, 0);
            }
        }
    }

#pragma unroll
    for (int ti = 0; ti < 2; ++ti) {
#pragma unroll
        for (int reg = 0; reg < 4; ++reg) {
            float s = l[ti][reg];
            s += __shfl_xor(s, 1);
            s += __shfl_xor(s, 2);
            s += __shfl_xor(s, 4);
            s += __shfl_xor(s, 8);
            float inv = 1.0f / s;
            int row = 16 * tiles[ti] + 4 * qd + reg;
            float* dst = out + ((size_t)b * T_DIM + row) * HEAD;
#pragma unroll
            for (int dn = 0; dn < 4; ++dn)
                dst[16 * dn + l15] = O[ti][dn][reg] * inv;
        }
    }
}

// ---------------------------------------------------------------------------
extern "C" void kernel_launch(void* const* d_in, const int* in_sizes, int n_in,
                              void* d_out, int out_size, void* d_ws, size_t ws_size,
                              hipStream_t stream) {
    const float* x  = (const float*)d_in[0];
    const float* Wq = (const float*)d_in[1];
    const float* Wk = (const float*)d_in[2];
    const float* Wv = (const float*)d_in[3];
    float* out = (float*)d_out;

    unsigned short* Wb = (unsigned short*)d_ws;   // 9216*8 bf16 = 147 KB

    wprep_kernel<<<36, 256, 0, stream>>>(Wq, Wk, Wv, Wb);
    fused_kernel<<<B_DIM, 512, 0, stream>>>(x, Wb, out);
}